// Round 1
// baseline (1141.048 us; speedup 1.0000x reference)
//
#include <hip/hip_runtime.h>

#define N_NODES 100000
#define N_EDGES 1000000
#define N_GRAPHS 1000
#define EMBED 64
#define OUT_DIM 128
#define BN_EPS 1e-5f

// ---------------- kernels ----------------

__global__ void embed_kernel(const int* __restrict__ nfeat,
                             const float* __restrict__ atom_embed,
                             float* __restrict__ h) {
    int idx = blockIdx.x * blockDim.x + threadIdx.x;
    if (idx >= N_NODES * EMBED) return;
    int v = idx >> 6, d = idx & 63;
    h[idx] = atom_embed[nfeat[v] * EMBED + d];
}

__global__ void deg_kernel(const int* __restrict__ dst, float* __restrict__ deg) {
    int e = blockIdx.x * blockDim.x + threadIdx.x;
    if (e < N_EDGES) atomicAdd(&deg[dst[e]], 1.0f);
}

__global__ void gcnt_kernel(const int* __restrict__ gid, float* __restrict__ gcnt) {
    int v = blockIdx.x * blockDim.x + threadIdx.x;
    if (v < N_NODES) atomicAdd(&gcnt[gid[v]], 1.0f);
}

// one wave per edge, lane = embedding dim
__global__ void edge_kernel(const int* __restrict__ efeat,
                            const int* __restrict__ src,
                            const int* __restrict__ dst,
                            const float* __restrict__ bond,   // [5,64] for this layer
                            const float* __restrict__ h,
                            float* __restrict__ agg) {
    int wid  = (blockIdx.x * blockDim.x + threadIdx.x) >> 6;
    int lane = threadIdx.x & 63;
    if (wid >= N_EDGES) return;
    int s = src[wid], t = dst[wid], b = efeat[wid];
    float v = bond[b * EMBED + lane] + h[s * EMBED + lane];
    v = fmaxf(v, 0.0f);
    atomicAdd(&agg[t * EMBED + lane], v);
}

// t = agg/deg + h; h_pre = t @ W + b; accumulate column sum/sumsq for BN
__launch_bounds__(256)
__global__ void node_update_kernel(const float* __restrict__ h,
                                   const float* __restrict__ agg,
                                   const float* __restrict__ deg,
                                   const float* __restrict__ W,    // [64,64]
                                   const float* __restrict__ bvec, // [64]
                                   float* __restrict__ h_pre,
                                   float* __restrict__ colsum,
                                   float* __restrict__ colsumsq) {
    __shared__ float Ws[EMBED * EMBED];
    __shared__ float ts[4][EMBED];
    __shared__ float red[2][4][EMBED];

    int j   = threadIdx.x & 63;
    int grp = threadIdx.x >> 6;

    for (int i = threadIdx.x; i < EMBED * EMBED; i += 256) Ws[i] = W[i];
    __syncthreads();

    float lsum = 0.0f, lsq = 0.0f;
    for (int base = blockIdx.x * 4; base < N_NODES; base += gridDim.x * 4) {
        int v = base + grp;
        if (v < N_NODES) {
            float d = deg[v];
            ts[grp][j] = agg[v * EMBED + j] / fmaxf(d, 1.0f) + h[v * EMBED + j];
        }
        __syncthreads();
        if (v < N_NODES) {
            float acc = bvec[j];
#pragma unroll
            for (int d = 0; d < EMBED; ++d)
                acc += ts[grp][d] * Ws[d * EMBED + j];
            h_pre[v * EMBED + j] = acc;
            lsum += acc;
            lsq  += acc * acc;
        }
        __syncthreads();
    }

    red[0][grp][j] = lsum;
    red[1][grp][j] = lsq;
    __syncthreads();
    if (grp == 0) {
        float s = red[0][0][j] + red[0][1][j] + red[0][2][j] + red[0][3][j];
        float q = red[1][0][j] + red[1][1][j] + red[1][2][j] + red[1][3][j];
        atomicAdd(&colsum[j], s);
        atomicAdd(&colsumsq[j], q);
    }
}

// batchnorm + optional relu + residual (in-place update of h)
__global__ void bn_kernel(const float* __restrict__ h_pre,
                          const float* __restrict__ colsum,
                          const float* __restrict__ colsumsq,
                          const float* __restrict__ gamma,
                          const float* __restrict__ beta,
                          float* __restrict__ h,
                          int do_relu) {
    int idx = blockIdx.x * blockDim.x + threadIdx.x;
    if (idx >= N_NODES * EMBED) return;
    int j = idx & 63;
    const float invN = 1.0f / (float)N_NODES;
    float mu  = colsum[j] * invN;
    float var = colsumsq[j] * invN - mu * mu;
    float inv = rsqrtf(var + BN_EPS);
    float y = (h_pre[idx] - mu) * inv * gamma[j] + beta[j];
    if (do_relu) y = fmaxf(y, 0.0f);
    h[idx] = y + h[idx];
}

// one wave per node: scatter into per-graph sums
__global__ void pool_kernel(const int* __restrict__ gid,
                            const float* __restrict__ h,
                            float* __restrict__ gsum) {
    int wid  = (blockIdx.x * blockDim.x + threadIdx.x) >> 6;
    int lane = threadIdx.x & 63;
    if (wid >= N_NODES) return;
    int g = gid[wid];
    atomicAdd(&gsum[g * EMBED + lane], h[wid * EMBED + lane]);
}

// [1000,64] @ [64,128] + b, one block (128 threads) per graph
__global__ void pred_kernel(const float* __restrict__ gsum,
                            const float* __restrict__ gcnt,
                            const float* __restrict__ W,   // [64,128]
                            const float* __restrict__ b,   // [128]
                            float* __restrict__ out) {
    __shared__ float gm[EMBED];
    int g = blockIdx.x;
    int j = threadIdx.x;  // 0..127
    if (j < EMBED) gm[j] = gsum[g * EMBED + j] / fmaxf(gcnt[g], 1.0f);
    __syncthreads();
    float acc = b[j];
#pragma unroll
    for (int d = 0; d < EMBED; ++d)
        acc += gm[d] * W[d * OUT_DIM + j];
    out[g * OUT_DIM + j] = acc;
}

// ---------------- launch ----------------

extern "C" void kernel_launch(void* const* d_in, const int* in_sizes, int n_in,
                              void* d_out, int out_size, void* d_ws, size_t ws_size,
                              hipStream_t stream) {
    const int*   nfeat      = (const int*)d_in[0];
    const int*   efeat      = (const int*)d_in[1];
    const int*   src        = (const int*)d_in[2];
    const int*   dst        = (const int*)d_in[3];
    const int*   gid        = (const int*)d_in[4];
    const float* atom_embed = (const float*)d_in[5];
    const float* bond_embed = (const float*)d_in[6];  // [3,5,64]
    const float* conv_W     = (const float*)d_in[7];  // [3,64,64]
    const float* conv_b     = (const float*)d_in[8];  // [3,64]
    const float* bn_gamma   = (const float*)d_in[9];  // [3,64]
    const float* bn_beta    = (const float*)d_in[10]; // [3,64]
    const float* pred_W     = (const float*)d_in[11]; // [64,128]
    const float* pred_b     = (const float*)d_in[12]; // [128]
    float* out = (float*)d_out;

    float* ws     = (float*)d_ws;
    float* h      = ws;                  // 6,400,000
    float* h_pre  = h + N_NODES * EMBED; // 6,400,000
    float* agg    = h_pre + N_NODES * EMBED;
    float* deg    = agg + N_NODES * EMBED; // 100,000
    float* gsum   = deg + N_NODES;         // 64,000
    float* gcnt   = gsum + N_GRAPHS * EMBED; // 1,000
    float* colsum = gcnt + N_GRAPHS;       // 64
    float* colsq  = colsum + EMBED;        // 64

    // zero the scratch we accumulate into
    hipMemsetAsync(deg,  0, N_NODES * sizeof(float), stream);
    hipMemsetAsync(gsum, 0, (N_GRAPHS * EMBED + N_GRAPHS) * sizeof(float), stream); // gsum+gcnt

    embed_kernel<<<(N_NODES * EMBED + 255) / 256, 256, 0, stream>>>(nfeat, atom_embed, h);
    deg_kernel<<<(N_EDGES + 255) / 256, 256, 0, stream>>>(dst, deg);
    gcnt_kernel<<<(N_NODES + 255) / 256, 256, 0, stream>>>(gid, gcnt);

    for (int i = 0; i < 3; ++i) {
        hipMemsetAsync(agg, 0, N_NODES * EMBED * sizeof(float), stream);
        hipMemsetAsync(colsum, 0, 2 * EMBED * sizeof(float), stream);

        edge_kernel<<<(N_EDGES * 64 + 255) / 256, 256, 0, stream>>>(
            efeat, src, dst, bond_embed + i * 5 * EMBED, h, agg);

        node_update_kernel<<<1024, 256, 0, stream>>>(
            h, agg, deg, conv_W + i * EMBED * EMBED, conv_b + i * EMBED,
            h_pre, colsum, colsq);

        bn_kernel<<<(N_NODES * EMBED + 255) / 256, 256, 0, stream>>>(
            h_pre, colsum, colsq, bn_gamma + i * EMBED, bn_beta + i * EMBED,
            h, /*do_relu=*/(i != 2) ? 1 : 0);
    }

    pool_kernel<<<(N_NODES * 64 + 255) / 256, 256, 0, stream>>>(gid, h, gsum);
    pred_kernel<<<N_GRAPHS, OUT_DIM, 0, stream>>>(gsum, gcnt, pred_W, pred_b, out);
}

// Round 2
// 952.045 us; speedup vs baseline: 1.1985x; 1.1985x over previous
//
#include <hip/hip_runtime.h>

#define N_NODES 100000
#define N_EDGES 1000000
#define N_GRAPHS 1000
#define EMBED 64
#define OUT_DIM 128
#define BN_EPS 1e-5f
#define NBLK ((N_NODES + 255) / 256)   // 391 scan blocks

// ---------------- one-time structure kernels ----------------

__global__ void embed_kernel(const int* __restrict__ nfeat,
                             const float* __restrict__ atom_embed,
                             float* __restrict__ h) {
    int idx = blockIdx.x * blockDim.x + threadIdx.x;
    if (idx >= N_NODES * EMBED) return;
    int v = idx >> 6, d = idx & 63;
    h[idx] = atom_embed[nfeat[v] * EMBED + d];
}

__global__ void deg_kernel(const int* __restrict__ dst, int* __restrict__ deg) {
    int e = blockIdx.x * blockDim.x + threadIdx.x;
    if (e < N_EDGES) atomicAdd(&deg[dst[e]], 1);
}

__global__ void scan1_kernel(const int* __restrict__ deg, int* __restrict__ bsum) {
    __shared__ int sm[256];
    int v = blockIdx.x * 256 + threadIdx.x;
    sm[threadIdx.x] = (v < N_NODES) ? deg[v] : 0;
    __syncthreads();
    for (int off = 128; off > 0; off >>= 1) {
        if (threadIdx.x < off) sm[threadIdx.x] += sm[threadIdx.x + off];
        __syncthreads();
    }
    if (threadIdx.x == 0) bsum[blockIdx.x] = sm[0];
}

__global__ void scan2_kernel(const int* __restrict__ bsum, int* __restrict__ bpre) {
    __shared__ int sm[512];
    int i = threadIdx.x;
    int orig = (i < NBLK) ? bsum[i] : 0;
    sm[i] = orig;
    __syncthreads();
    for (int off = 1; off < 512; off <<= 1) {
        int val = sm[i];
        if (i >= off) val += sm[i - off];
        __syncthreads();
        sm[i] = val;
        __syncthreads();
    }
    if (i < NBLK) bpre[i] = sm[i] - orig;   // exclusive prefix of block sums
}

__global__ void scan3_kernel(const int* __restrict__ deg, const int* __restrict__ bpre,
                             int* __restrict__ rowptr, int* __restrict__ cursor) {
    __shared__ int sm[256];
    int v = blockIdx.x * 256 + threadIdx.x;
    int d = (v < N_NODES) ? deg[v] : 0;
    sm[threadIdx.x] = d;
    __syncthreads();
    for (int off = 1; off < 256; off <<= 1) {
        int val = sm[threadIdx.x];
        if (threadIdx.x >= off) val += sm[threadIdx.x - off];
        __syncthreads();
        sm[threadIdx.x] = val;
        __syncthreads();
    }
    if (v < N_NODES) {
        int ex = bpre[blockIdx.x] + sm[threadIdx.x] - d;  // exclusive scan
        rowptr[v] = ex;
        cursor[v] = ex;
    }
    if (v == 0) rowptr[N_NODES] = N_EDGES;
}

// bucket edges by dst; payload packs src (20 bits) + efeat (bits 20+)
__global__ void scatter_kernel(const int* __restrict__ src, const int* __restrict__ dst,
                               const int* __restrict__ efeat,
                               int* __restrict__ cursor, unsigned* __restrict__ ebuf) {
    int e = blockIdx.x * blockDim.x + threadIdx.x;
    if (e >= N_EDGES) return;
    int t = dst[e];
    int pos = atomicAdd(&cursor[t], 1);
    ebuf[pos] = (unsigned)src[e] | ((unsigned)efeat[e] << 20);
}

// graph_ids is sorted: find segment boundaries. gstart has N_GRAPHS+1 entries.
__global__ void gbound_kernel(const int* __restrict__ gid, int* __restrict__ gstart) {
    int v = blockIdx.x * blockDim.x + threadIdx.x;
    if (v > N_NODES) return;
    int cur  = (v < N_NODES) ? gid[v] : N_GRAPHS;
    int prev = (v == 0) ? -1 : gid[v - 1];
    for (int g = prev + 1; g <= cur; ++g) gstart[g] = v;
}

// ---------------- per-layer fused conv ----------------
// One wave per node: gather+relu+mean aggregate (registers), +h residual-in,
// 64x64 GEMM via shfl-broadcast against LDS W, BN column partial sums.
__launch_bounds__(256)
__global__ void fused_conv_kernel(const int* __restrict__ rowptr,
                                  const unsigned* __restrict__ ebuf,
                                  const float* __restrict__ bond,   // [5,64]
                                  const float* __restrict__ h,
                                  const float* __restrict__ W,      // [64,64]
                                  const float* __restrict__ bias,   // [64]
                                  float* __restrict__ h_pre,
                                  float* __restrict__ colsum,
                                  float* __restrict__ colsq) {
    __shared__ float Ws[EMBED * EMBED];
    __shared__ float bond_s[5 * EMBED];
    __shared__ float red[2][4][EMBED];

    int lane = threadIdx.x & 63;
    int wblk = threadIdx.x >> 6;

    for (int i = threadIdx.x; i < EMBED * EMBED; i += 256) Ws[i] = W[i];
    for (int i = threadIdx.x; i < 5 * EMBED; i += 256) bond_s[i] = bond[i];
    __syncthreads();

    float bj = bias[lane];
    float lsum = 0.0f, lsq = 0.0f;

    int gwid = blockIdx.x * 4 + wblk;
    int nw   = gridDim.x * 4;
    for (int v = gwid; v < N_NODES; v += nw) {
        int rb = rowptr[v], re = rowptr[v + 1];
        float t = 0.0f;
        for (int e = rb; e < re; ++e) {
            unsigned p = ebuf[e];
            int s = (int)(p & 0xFFFFFu);
            int b = (int)(p >> 20);
            float val = bond_s[b * EMBED + lane] + h[s * EMBED + lane];
            t += fmaxf(val, 0.0f);
        }
        int dg = re - rb;
        t = t / fmaxf((float)dg, 1.0f) + h[v * EMBED + lane];

        float acc = bj;
#pragma unroll
        for (int d = 0; d < EMBED; ++d)
            acc += __shfl(t, d) * Ws[d * EMBED + lane];

        h_pre[v * EMBED + lane] = acc;
        lsum += acc;
        lsq  += acc * acc;
    }

    red[0][wblk][lane] = lsum;
    red[1][wblk][lane] = lsq;
    __syncthreads();
    if (wblk == 0) {
        float s = red[0][0][lane] + red[0][1][lane] + red[0][2][lane] + red[0][3][lane];
        float q = red[1][0][lane] + red[1][1][lane] + red[1][2][lane] + red[1][3][lane];
        atomicAdd(&colsum[lane], s);
        atomicAdd(&colsq[lane], q);
    }
}

// batchnorm + optional relu + residual (in-place update of h)
__global__ void bn_kernel(const float* __restrict__ h_pre,
                          const float* __restrict__ colsum,
                          const float* __restrict__ colsq,
                          const float* __restrict__ gamma,
                          const float* __restrict__ beta,
                          float* __restrict__ h,
                          int do_relu) {
    int idx = blockIdx.x * blockDim.x + threadIdx.x;
    if (idx >= N_NODES * EMBED) return;
    int j = idx & 63;
    const float invN = 1.0f / (float)N_NODES;
    float mu  = colsum[j] * invN;
    float var = colsq[j] * invN - mu * mu;
    float inv = rsqrtf(var + BN_EPS);
    float y = (h_pre[idx] - mu) * inv * gamma[j] + beta[j];
    if (do_relu) y = fmaxf(y, 0.0f);
    h[idx] = y + h[idx];
}

// one wave per graph: sequential coalesced mean over its node range (gid sorted)
__global__ void pool_kernel(const int* __restrict__ gstart,
                            const float* __restrict__ h,
                            float* __restrict__ gmean) {
    int g    = (blockIdx.x * blockDim.x + threadIdx.x) >> 6;
    int lane = threadIdx.x & 63;
    if (g >= N_GRAPHS) return;
    int b = gstart[g], e = gstart[g + 1];
    float s = 0.0f;
    for (int v = b; v < e; ++v) s += h[v * EMBED + lane];
    gmean[g * EMBED + lane] = s / fmaxf((float)(e - b), 1.0f);
}

// [1000,64] @ [64,128] + b, one block (128 threads) per graph
__global__ void pred_kernel(const float* __restrict__ gmean,
                            const float* __restrict__ W,   // [64,128]
                            const float* __restrict__ b,   // [128]
                            float* __restrict__ out) {
    __shared__ float gm[EMBED];
    int g = blockIdx.x;
    int j = threadIdx.x;  // 0..127
    if (j < EMBED) gm[j] = gmean[g * EMBED + j];
    __syncthreads();
    float acc = b[j];
#pragma unroll
    for (int d = 0; d < EMBED; ++d)
        acc += gm[d] * W[d * OUT_DIM + j];
    out[g * OUT_DIM + j] = acc;
}

// ---------------- launch ----------------

extern "C" void kernel_launch(void* const* d_in, const int* in_sizes, int n_in,
                              void* d_out, int out_size, void* d_ws, size_t ws_size,
                              hipStream_t stream) {
    const int*   nfeat      = (const int*)d_in[0];
    const int*   efeat      = (const int*)d_in[1];
    const int*   src        = (const int*)d_in[2];
    const int*   dst        = (const int*)d_in[3];
    const int*   gid        = (const int*)d_in[4];
    const float* atom_embed = (const float*)d_in[5];
    const float* bond_embed = (const float*)d_in[6];  // [3,5,64]
    const float* conv_W     = (const float*)d_in[7];  // [3,64,64]
    const float* conv_b     = (const float*)d_in[8];  // [3,64]
    const float* bn_gamma   = (const float*)d_in[9];  // [3,64]
    const float* bn_beta    = (const float*)d_in[10]; // [3,64]
    const float* pred_W     = (const float*)d_in[11]; // [64,128]
    const float* pred_b     = (const float*)d_in[12]; // [128]
    float* out = (float*)d_out;

    // workspace carve-up (floats are 4B, ints are 4B)
    char* wsb = (char*)d_ws;
    float*    h      = (float*)wsb;                     wsb += (size_t)N_NODES * EMBED * 4;
    float*    h_pre  = (float*)wsb;                     wsb += (size_t)N_NODES * EMBED * 4;
    int*      deg    = (int*)wsb;                       wsb += (size_t)N_NODES * 4;
    int*      rowptr = (int*)wsb;                       wsb += (size_t)(N_NODES + 1) * 4;
    int*      cursor = (int*)wsb;                       wsb += (size_t)N_NODES * 4;
    int*      bsum   = (int*)wsb;                       wsb += (size_t)NBLK * 4;
    int*      bpre   = (int*)wsb;                       wsb += (size_t)NBLK * 4;
    unsigned* ebuf   = (unsigned*)wsb;                  wsb += (size_t)N_EDGES * 4;
    int*      gstart = (int*)wsb;                       wsb += (size_t)(N_GRAPHS + 1) * 4;
    float*    gmean  = (float*)wsb;                     wsb += (size_t)N_GRAPHS * EMBED * 4;
    float*    colsum = (float*)wsb;                     wsb += (size_t)EMBED * 4;
    float*    colsq  = (float*)wsb;                     wsb += (size_t)EMBED * 4;

    hipMemsetAsync(deg, 0, N_NODES * sizeof(int), stream);

    embed_kernel<<<(N_NODES * EMBED + 255) / 256, 256, 0, stream>>>(nfeat, atom_embed, h);
    deg_kernel<<<(N_EDGES + 255) / 256, 256, 0, stream>>>(dst, deg);
    scan1_kernel<<<NBLK, 256, 0, stream>>>(deg, bsum);
    scan2_kernel<<<1, 512, 0, stream>>>(bsum, bpre);
    scan3_kernel<<<NBLK, 256, 0, stream>>>(deg, bpre, rowptr, cursor);
    scatter_kernel<<<(N_EDGES + 255) / 256, 256, 0, stream>>>(src, dst, efeat, cursor, ebuf);
    gbound_kernel<<<(N_NODES + 256) / 256, 256, 0, stream>>>(gid, gstart);

    for (int i = 0; i < 3; ++i) {
        hipMemsetAsync(colsum, 0, 2 * EMBED * sizeof(float), stream);  // colsum+colsq
        fused_conv_kernel<<<2048, 256, 0, stream>>>(
            rowptr, ebuf, bond_embed + i * 5 * EMBED, h,
            conv_W + i * EMBED * EMBED, conv_b + i * EMBED,
            h_pre, colsum, colsq);
        bn_kernel<<<(N_NODES * EMBED + 255) / 256, 256, 0, stream>>>(
            h_pre, colsum, colsq, bn_gamma + i * EMBED, bn_beta + i * EMBED,
            h, (i != 2) ? 1 : 0);
    }

    pool_kernel<<<(N_GRAPHS * 64 + 255) / 256, 256, 0, stream>>>(gstart, h, gmean);
    pred_kernel<<<N_GRAPHS, OUT_DIM, 0, stream>>>(gmean, pred_W, pred_b, out);
}